// Round 1
// baseline (483.720 us; speedup 1.0000x reference)
//
#include <hip/hip_runtime.h>
#include <stdint.h>

#define DEVI __device__ __forceinline__

typedef float        f32x4  __attribute__((ext_vector_type(4)));
typedef __bf16       bf16x8 __attribute__((ext_vector_type(8)));
typedef unsigned short u16x8 __attribute__((ext_vector_type(8)));

static constexpr int TSEQ   = 2048;
static constexpr int NSTATE = 1024;
static constexpr int NHEAD  = 16;
static constexpr int DHEAD  = 64;
static constexpr int BATCH  = 4;
static constexpr int MROWS  = BATCH * TSEQ;              // 8192
static constexpr float SCALE = 0.35355339059327373f;     // 64^-0.25

DEVI unsigned short f2bf(float f) {
  union { float f; uint32_t u; } v; v.f = f;
  return (unsigned short)((v.u + 0x7fffu + ((v.u >> 16) & 1u)) >> 16);
}
DEVI float bf2f(unsigned short s) {
  union { uint32_t u; float f; } v; v.u = ((uint32_t)s) << 16;
  return v.f;
}

DEVI f32x4 mfma16(u16x8 a, u16x8 b, f32x4 c) {
  return __builtin_amdgcn_mfma_f32_16x16x32_bf16(
      __builtin_bit_cast(bf16x8, a), __builtin_bit_cast(bf16x8, b), c, 0, 0, 0);
}

DEVI void gload_lds16(const void* g, void* l) {
  __builtin_amdgcn_global_load_lds(
      (const __attribute__((address_space(1))) void*)g,
      (__attribute__((address_space(3))) void*)l, 16, 0, 0);
}

// ---------------- f32 -> bf16 conversion ----------------
__global__ void cvt_kernel(const float* __restrict__ in,
                           unsigned short* __restrict__ out, int n4) {
  int i = blockIdx.x * blockDim.x + threadIdx.x;
  const int stride = gridDim.x * blockDim.x;
  for (; i < n4; i += stride) {
    const float4 f = ((const float4*)in)[i];
    ushort4 o;
    o.x = f2bf(f.x); o.y = f2bf(f.y); o.z = f2bf(f.z); o.w = f2bf(f.w);
    ((ushort4*)out)[i] = o;
  }
}

// ---------------- GEMM: C[m][n] = sum_k A[m][k] * W[n][k] (+bias, epilogue) ----
// MODE 0: Q = (acc+bias)*SCALE -> bf16 scatter (B,H,T,D)
// MODE 1: K = acc*SCALE        -> bf16 scatter (B,H,T,D)
// MODE 2: V = acc+bias         -> bf16 scatter (B,H,T,D)
// MODE 3: O = acc+bias         -> f32 row-major [M][N]
template<int MODE>
__global__ __launch_bounds__(256)
void gemm_bt(const unsigned short* __restrict__ A,
             const unsigned short* __restrict__ Bw,
             const float* __restrict__ bias,
             void* __restrict__ out)
{
  __shared__ __align__(16) unsigned short As[128 * 32];
  __shared__ __align__(16) unsigned short Bs[128 * 32];
  const int t  = threadIdx.x;
  const int l  = t & 63, w = t >> 6;
  const int fr = l & 15, fq = l >> 4;
  const int m0 = blockIdx.y * 128, n0 = blockIdx.x * 128;
  const int wm = (w & 1) * 64, wn = (w >> 1) * 64;

  f32x4 acc[4][4] = {};

  const int sr = t >> 2;          // 0..63
  const int sc = (t & 3) * 8;     // 0,8,16,24
  const unsigned short* ag = A  + (size_t)(m0 + sr) * NSTATE + sc;
  const unsigned short* bg = Bw + (size_t)(n0 + sr) * NSTATE + sc;
  unsigned short* lA0 = As + t * 8;
  unsigned short* lA1 = As + 2048 + t * 8;
  unsigned short* lB0 = Bs + t * 8;
  unsigned short* lB1 = Bs + 2048 + t * 8;

  for (int kt = 0; kt < NSTATE / 32; ++kt) {
    const int ko = kt * 32;
    gload_lds16(ag + ko,               lA0);
    gload_lds16(ag + 64 * NSTATE + ko, lA1);
    gload_lds16(bg + ko,               lB0);
    gload_lds16(bg + 64 * NSTATE + ko, lB1);
    __syncthreads();

    u16x8 a[4], b[4];
    #pragma unroll
    for (int i = 0; i < 4; ++i)
      a[i] = *(const u16x8*)(As + (wm + i * 16 + fr) * 32 + fq * 8);
    #pragma unroll
    for (int j = 0; j < 4; ++j)
      b[j] = *(const u16x8*)(Bs + (wn + j * 16 + fr) * 32 + fq * 8);
    #pragma unroll
    for (int i = 0; i < 4; ++i)
      #pragma unroll
      for (int j = 0; j < 4; ++j)
        acc[i][j] = mfma16(a[i], b[j], acc[i][j]);
    __syncthreads();
  }

  if (MODE == 3) {
    float* Co = (float*)out;
    #pragma unroll
    for (int j = 0; j < 4; ++j) {
      const int col = n0 + wn + j * 16 + fr;
      const float bj = bias[col];
      #pragma unroll
      for (int i = 0; i < 4; ++i) {
        const int row0 = m0 + wm + i * 16 + fq * 4;
        #pragma unroll
        for (int r = 0; r < 4; ++r)
          Co[(size_t)(row0 + r) * NSTATE + col] = acc[i][j][r] + bj;
      }
    }
  } else {
    unsigned short* Cq = (unsigned short*)out;
    const int h = (n0 + wn) >> 6;      // head is uniform per (block, wave)
    #pragma unroll
    for (int j = 0; j < 4; ++j) {
      const int d = j * 16 + fr;       // 0..63
      const float bj = (MODE == 1) ? 0.0f : bias[n0 + wn + d];
      #pragma unroll
      for (int i = 0; i < 4; ++i) {
        #pragma unroll
        for (int r = 0; r < 4; ++r) {
          const int row = m0 + wm + i * 16 + fq * 4 + r;   // m = b*T + t
          const int bb = row >> 11, tt = row & (TSEQ - 1);
          float v = acc[i][j][r];
          if (MODE == 0)      v = (v + bj) * SCALE;
          else if (MODE == 1) v = v * SCALE;
          else                v = v + bj;
          Cq[(((size_t)(bb * NHEAD + h)) * TSEQ + tt) * DHEAD + d] = f2bf(v);
        }
      }
    }
  }
}

// ---------------- flash attention (causal), Q/K/V bf16 in (B,H,T,D) ----------
// grid: x = T/64 q-blocks, y = B*H.  block = 256 thr = 4 waves, 16 q-rows/wave.
__global__ __launch_bounds__(256)
void flash_attn(const unsigned short* __restrict__ Qg,
                const unsigned short* __restrict__ Kg,
                const unsigned short* __restrict__ Vg,
                unsigned short* __restrict__ O)
{
  const int qb = blockIdx.x, bh = blockIdx.y;
  const int b  = bh >> 4, h = bh & 15;
  const int t  = threadIdx.x, l = t & 63, w = t >> 6;
  const int fr = l & 15, fq = l >> 4;
  const size_t hoff = (size_t)bh * TSEQ * DHEAD;
  const unsigned short* Qp = Qg + hoff;
  const unsigned short* Kp = Kg + hoff;
  const unsigned short* Vp = Vg + hoff;

  __shared__ __align__(16) unsigned short Vt[64][72];      // V^T, padded stride
  __shared__ __align__(16) unsigned short Pl[4][16][72];   // per-wave P

  const int qw = qb * 64 + w * 16;
  const u16x8 q0 = *(const u16x8*)(Qp + (size_t)(qw + fr) * DHEAD + fq * 8);
  const u16x8 q1 = *(const u16x8*)(Qp + (size_t)(qw + fr) * DHEAD + 32 + fq * 8);

  f32x4 oacc[4] = {};
  float mrow[4], lrow[4];
  #pragma unroll
  for (int r = 0; r < 4; ++r) { mrow[r] = -1e30f; lrow[r] = 0.0f; }

  const int nkt = qb * 2 + 2;
  for (int kt = 0; kt < nkt; ++kt) {
    const int k0 = kt * 32;
    __syncthreads();                       // protect Vt from previous readers
    {
      const int vk = t & 31, vd = (t >> 5) * 8;
      const u16x8 vv = *(const u16x8*)(Vp + (size_t)(k0 + vk) * DHEAD + vd);
      #pragma unroll
      for (int i = 0; i < 8; ++i) Vt[vd + i][vk] = vv[i];
    }
    __syncthreads();

    // S = (Q*scale)(K*scale)^T, two 16-col subtiles
    f32x4 s[2];
    #pragma unroll
    for (int sc = 0; sc < 2; ++sc) {
      const unsigned short* kr = Kp + (size_t)(k0 + sc * 16 + fr) * DHEAD + fq * 8;
      const u16x8 kf0 = *(const u16x8*)kr;
      const u16x8 kf1 = *(const u16x8*)(kr + 32);
      f32x4 z = {0.f, 0.f, 0.f, 0.f};
      z = mfma16(q0, kf0, z);
      z = mfma16(q1, kf1, z);
      s[sc] = z;
    }
    if (k0 + 31 > qw) {                    // tile crosses the diagonal
      #pragma unroll
      for (int sc = 0; sc < 2; ++sc)
        #pragma unroll
        for (int r = 0; r < 4; ++r) {
          const int kcol = k0 + sc * 16 + fr;
          const int qrow = qw + fq * 4 + r;
          if (kcol > qrow) s[sc][r] = -1e30f;
        }
    }

    float corr[4];
    #pragma unroll
    for (int r = 0; r < 4; ++r) {
      float mx = fmaxf(s[0][r], s[1][r]);
      mx = fmaxf(mx, __shfl_xor(mx, 1));
      mx = fmaxf(mx, __shfl_xor(mx, 2));
      mx = fmaxf(mx, __shfl_xor(mx, 4));
      mx = fmaxf(mx, __shfl_xor(mx, 8));
      const float mnew = fmaxf(mrow[r], mx);
      const float c  = __expf(mrow[r] - mnew);
      float p0 = __expf(s[0][r] - mnew);
      float p1 = __expf(s[1][r] - mnew);
      const unsigned short p0b = f2bf(p0), p1b = f2bf(p1);
      p0 = bf2f(p0b); p1 = bf2f(p1b);      // denominator matches bf16 numerator
      mrow[r] = mnew;
      corr[r] = c;
      float ps = p0 + p1;
      ps += __shfl_xor(ps, 1);
      ps += __shfl_xor(ps, 2);
      ps += __shfl_xor(ps, 4);
      ps += __shfl_xor(ps, 8);
      lrow[r] = lrow[r] * c + ps;
      Pl[w][fq * 4 + r][fr]      = p0b;
      Pl[w][fq * 4 + r][16 + fr] = p1b;
    }
    #pragma unroll
    for (int j = 0; j < 4; ++j)
      #pragma unroll
      for (int r = 0; r < 4; ++r) oacc[j][r] *= corr[r];

    const u16x8 pf = *(const u16x8*)(&Pl[w][fr][fq * 8]);
    #pragma unroll
    for (int j = 0; j < 4; ++j) {
      const u16x8 vf = *(const u16x8*)(&Vt[j * 16 + fr][fq * 8]);
      oacc[j] = mfma16(pf, vf, oacc[j]);
    }
  }

  #pragma unroll
  for (int r = 0; r < 4; ++r) {
    const float inv = 1.0f / lrow[r];
    const int qg = qw + fq * 4 + r;
    const size_t base = ((size_t)(b * TSEQ + qg)) * NSTATE + h * DHEAD;
    #pragma unroll
    for (int j = 0; j < 4; ++j)
      O[base + j * 16 + fr] = f2bf(oacc[j][r] * inv);
  }
}

// ---------------- launcher ----------------
extern "C" void kernel_launch(void* const* d_in, const int* in_sizes, int n_in,
                              void* d_out, int out_size, void* d_ws, size_t ws_size,
                              hipStream_t stream)
{
  (void)in_sizes; (void)n_in; (void)out_size; (void)ws_size;
  const float* x  = (const float*)d_in[0];
  // d_in[1] = mask (pure causal -1e9 tril; implemented analytically)
  const float* Wq = (const float*)d_in[2];
  const float* bq = (const float*)d_in[3];
  const float* Wk = (const float*)d_in[4];
  const float* Wv = (const float*)d_in[5];
  const float* bv = (const float*)d_in[6];
  const float* Wo = (const float*)d_in[7];
  const float* bo = (const float*)d_in[8];

  char* ws = (char*)d_ws;
  unsigned short* xb  = (unsigned short*)(ws);               // 16MB (reused for attn out)
  unsigned short* wqb = (unsigned short*)(ws + (16u << 20));
  unsigned short* wkb = wqb + (1u << 20);
  unsigned short* wvb = wkb + (1u << 20);
  unsigned short* wob = wvb + (1u << 20);
  unsigned short* qb_ = (unsigned short*)(ws + (24u << 20)); // 16MB each
  unsigned short* kb_ = (unsigned short*)(ws + (40u << 20));
  unsigned short* vb_ = (unsigned short*)(ws + (56u << 20));

  cvt_kernel<<<2048, 256, 0, stream>>>(x,  xb,  MROWS * NSTATE / 4);
  cvt_kernel<<<512,  256, 0, stream>>>(Wq, wqb, NSTATE * NSTATE / 4);
  cvt_kernel<<<512,  256, 0, stream>>>(Wk, wkb, NSTATE * NSTATE / 4);
  cvt_kernel<<<512,  256, 0, stream>>>(Wv, wvb, NSTATE * NSTATE / 4);
  cvt_kernel<<<512,  256, 0, stream>>>(Wo, wob, NSTATE * NSTATE / 4);

  const dim3 gg(NSTATE / 128, MROWS / 128);
  gemm_bt<0><<<gg, 256, 0, stream>>>(xb, wqb, bq, qb_);
  gemm_bt<1><<<gg, 256, 0, stream>>>(xb, wkb, bq, kb_);
  gemm_bt<2><<<gg, 256, 0, stream>>>(xb, wvb, bv, vb_);

  flash_attn<<<dim3(TSEQ / 64, BATCH * NHEAD), 256, 0, stream>>>(qb_, kb_, vb_, xb);

  gemm_bt<3><<<gg, 256, 0, stream>>>(xb, wob, bo, d_out);
}

// Round 2
// 424.434 us; speedup vs baseline: 1.1397x; 1.1397x over previous
//
#include <hip/hip_runtime.h>
#include <stdint.h>

#define DEVI __device__ __forceinline__

typedef float        f32x4  __attribute__((ext_vector_type(4)));
typedef __bf16       bf16x8 __attribute__((ext_vector_type(8)));
typedef unsigned short u16x8 __attribute__((ext_vector_type(8)));
typedef unsigned short u16x4 __attribute__((ext_vector_type(4)));

static constexpr int TSEQ   = 2048;
static constexpr int NSTATE = 1024;
static constexpr int NHEAD  = 16;
static constexpr int DHEAD  = 64;
static constexpr int BATCH  = 4;
static constexpr int MROWS  = BATCH * TSEQ;              // 8192
static constexpr float SCALE = 0.35355339059327373f;     // 64^-0.25

DEVI unsigned short f2bf(float f) {
  union { float f; uint32_t u; } v; v.f = f;
  return (unsigned short)((v.u + 0x7fffu + ((v.u >> 16) & 1u)) >> 16);
}
DEVI float bf2f(unsigned short s) {
  union { uint32_t u; float f; } v; v.u = ((uint32_t)s) << 16;
  return v.f;
}

DEVI f32x4 mfma16(u16x8 a, u16x8 b, f32x4 c) {
  return __builtin_amdgcn_mfma_f32_16x16x32_bf16(
      __builtin_bit_cast(bf16x8, a), __builtin_bit_cast(bf16x8, b), c, 0, 0, 0);
}

DEVI void gload_lds16(const void* g, void* l) {
  __builtin_amdgcn_global_load_lds(
      (const __attribute__((address_space(1))) void*)g,
      (__attribute__((address_space(3))) void*)l, 16, 0, 0);
}

// ---------------- f32 -> bf16 conversion ----------------
__global__ void cvt_kernel(const float* __restrict__ in,
                           unsigned short* __restrict__ out, int n4) {
  int i = blockIdx.x * blockDim.x + threadIdx.x;
  const int stride = gridDim.x * blockDim.x;
  for (; i < n4; i += stride) {
    const float4 f = ((const float4*)in)[i];
    ushort4 o;
    o.x = f2bf(f.x); o.y = f2bf(f.y); o.z = f2bf(f.z); o.w = f2bf(f.w);
    ((ushort4*)out)[i] = o;
  }
}

// ---------------- GEMM: C[m][n] = sum_k A[m][k] * W[n][k] (+bias, epilogue) ----
// MODE 0: Q = (acc+bias)*SCALE -> bf16 scatter (B,H,T,D)
// MODE 1: K = acc*SCALE        -> bf16 scatter (B,H,T,D)
// MODE 2: V = acc+bias         -> bf16 scatter (B,H,T,D)
// MODE 3: O = acc+bias         -> f32 row-major [M][N]
template<int MODE>
__global__ __launch_bounds__(256)
void gemm_bt(const unsigned short* __restrict__ A,
             const unsigned short* __restrict__ Bw,
             const float* __restrict__ bias,
             void* __restrict__ out)
{
  __shared__ __align__(16) unsigned short As[128 * 32];
  __shared__ __align__(16) unsigned short Bs[128 * 32];
  const int t  = threadIdx.x;
  const int l  = t & 63, w = t >> 6;
  const int fr = l & 15, fq = l >> 4;
  const int m0 = blockIdx.y * 128, n0 = blockIdx.x * 128;
  const int wm = (w & 1) * 64, wn = (w >> 1) * 64;

  f32x4 acc[4][4] = {};

  const int sr = t >> 2;          // 0..63
  const int sc = (t & 3) * 8;     // 0,8,16,24
  const unsigned short* ag = A  + (size_t)(m0 + sr) * NSTATE + sc;
  const unsigned short* bg = Bw + (size_t)(n0 + sr) * NSTATE + sc;
  unsigned short* lA0 = As + t * 8;
  unsigned short* lA1 = As + 2048 + t * 8;
  unsigned short* lB0 = Bs + t * 8;
  unsigned short* lB1 = Bs + 2048 + t * 8;

  for (int kt = 0; kt < NSTATE / 32; ++kt) {
    const int ko = kt * 32;
    gload_lds16(ag + ko,               lA0);
    gload_lds16(ag + 64 * NSTATE + ko, lA1);
    gload_lds16(bg + ko,               lB0);
    gload_lds16(bg + 64 * NSTATE + ko, lB1);
    __syncthreads();

    u16x8 a[4], b[4];
    #pragma unroll
    for (int i = 0; i < 4; ++i)
      a[i] = *(const u16x8*)(As + (wm + i * 16 + fr) * 32 + fq * 8);
    #pragma unroll
    for (int j = 0; j < 4; ++j)
      b[j] = *(const u16x8*)(Bs + (wn + j * 16 + fr) * 32 + fq * 8);
    #pragma unroll
    for (int i = 0; i < 4; ++i)
      #pragma unroll
      for (int j = 0; j < 4; ++j)
        acc[i][j] = mfma16(a[i], b[j], acc[i][j]);
    __syncthreads();
  }

  if (MODE == 3) {
    float* Co = (float*)out;
    #pragma unroll
    for (int j = 0; j < 4; ++j) {
      const int col = n0 + wn + j * 16 + fr;
      const float bj = bias[col];
      #pragma unroll
      for (int i = 0; i < 4; ++i) {
        const int row0 = m0 + wm + i * 16 + fq * 4;
        #pragma unroll
        for (int r = 0; r < 4; ++r)
          Co[(size_t)(row0 + r) * NSTATE + col] = acc[i][j][r] + bj;
      }
    }
  } else {
    unsigned short* Cq = (unsigned short*)out;
    const int h = (n0 + wn) >> 6;      // head is uniform per (block, wave)
    #pragma unroll
    for (int j = 0; j < 4; ++j) {
      const int d = j * 16 + fr;       // 0..63
      const float bj = (MODE == 1) ? 0.0f : bias[n0 + wn + d];
      #pragma unroll
      for (int i = 0; i < 4; ++i) {
        #pragma unroll
        for (int r = 0; r < 4; ++r) {
          const int row = m0 + wm + i * 16 + fq * 4 + r;   // m = b*T + t
          const int bb = row >> 11, tt = row & (TSEQ - 1);
          float v = acc[i][j][r];
          if (MODE == 0)      v = (v + bj) * SCALE;
          else if (MODE == 1) v = v * SCALE;
          else                v = v + bj;
          Cq[(((size_t)(bb * NHEAD + h)) * TSEQ + tt) * DHEAD + d] = f2bf(v);
        }
      }
    }
  }
}

// ---------------- flash attention (causal), swapped-QK^T in-register softmax --
// grid: x = T/64 q-blocks (reversed: longest first), y = B*H.
// block = 256 thr = 4 waves, 16 q-rows/wave, KVBLK = 64.
// S^T = mfma(K, Q): lane (fr,fq) owns q-row qw+fr, k-strip st*16+fq*4+r.
__global__ __launch_bounds__(256)
void flash_attn(const unsigned short* __restrict__ Qg,
                const unsigned short* __restrict__ Kg,
                const unsigned short* __restrict__ Vg,
                unsigned short* __restrict__ O)
{
  const int qb = (int)gridDim.x - 1 - (int)blockIdx.x;   // longest blocks first
  const int bh = blockIdx.y;
  const int b  = bh >> 4, h = bh & 15;
  const int t  = threadIdx.x, l = t & 63, w = t >> 6;
  const int fr = l & 15, fq = l >> 4;
  const size_t hoff = (size_t)bh * TSEQ * DHEAD;
  const unsigned short* Qp = Qg + hoff;
  const unsigned short* Kp = Kg + hoff;
  const unsigned short* Vp = Vg + hoff;

  __shared__ __align__(16) unsigned short Vt[64][72];      // V^T: row=d, col=k
  __shared__ __align__(16) unsigned short Pw[4][16][72];   // per-wave P: row=q, col=k

  const int qw = qb * 64 + w * 16;       // wave's first q-row
  // Q fragments (B-operand): lane holds Q[qw+fr][fq*8..+7] and [+32..]
  const u16x8 q0 = *(const u16x8*)(Qp + (size_t)(qw + fr) * DHEAD + fq * 8);
  const u16x8 q1 = *(const u16x8*)(Qp + (size_t)(qw + fr) * DHEAD + 32 + fq * 8);

  f32x4 oacc[4] = {};                    // [dsub]: q = fq*4+reg, d = dsub*16+fr
  float m_r = -1e30f, l_r = 0.0f;        // per-lane softmax state for q = qw+fr

  const int vk = t & 63, vds = w * 16;   // V-stage assignment

  const int nkt = qb + 1;
  for (int kt = 0; kt < nkt; ++kt) {
    const int k0 = kt * 64;
    __syncthreads();                     // previous tile's Vt readers done
    {
      const u16x8 v0 = *(const u16x8*)(Vp + (size_t)(k0 + vk) * DHEAD + vds);
      const u16x8 v1 = *(const u16x8*)(Vp + (size_t)(k0 + vk) * DHEAD + vds + 8);
      #pragma unroll
      for (int i = 0; i < 8; ++i) Vt[vds + i][vk]     = v0[i];
      #pragma unroll
      for (int i = 0; i < 8; ++i) Vt[vds + 8 + i][vk] = v1[i];
    }
    __syncthreads();

    // S^T subtiles: s[st][r] = S[k0+st*16+fq*4+r][qw+fr]
    f32x4 s[4];
    #pragma unroll
    for (int st = 0; st < 4; ++st) {
      if (k0 + st * 16 <= qw + 15) {     // wave-uniform causal subtile skip
        const unsigned short* kr = Kp + (size_t)(k0 + st * 16 + fr) * DHEAD + fq * 8;
        const u16x8 kf0 = *(const u16x8*)kr;
        const u16x8 kf1 = *(const u16x8*)(kr + 32);
        f32x4 z = {0.f, 0.f, 0.f, 0.f};
        z = mfma16(kf0, q0, z);          // d = 0..31
        z = mfma16(kf1, q1, z);          // d = 32..63
        s[st] = z;
      } else {
        s[st] = (f32x4){-1e30f, -1e30f, -1e30f, -1e30f};
      }
    }
    if (k0 + 63 > qw) {                  // crossing tile: element mask
      #pragma unroll
      for (int st = 0; st < 4; ++st)
        #pragma unroll
        for (int r = 0; r < 4; ++r)
          if (k0 + st * 16 + fq * 4 + r > qw + fr) s[st][r] = -1e30f;
    }

    // row max: 15 in-lane + 2 shuffles (butterfly over fq bits)
    float mx = fmaxf(fmaxf(s[0][0], s[0][1]), fmaxf(s[0][2], s[0][3]));
    #pragma unroll
    for (int st = 1; st < 4; ++st)
      mx = fmaxf(mx, fmaxf(fmaxf(s[st][0], s[st][1]), fmaxf(s[st][2], s[st][3])));
    mx = fmaxf(mx, __shfl_xor(mx, 16));
    mx = fmaxf(mx, __shfl_xor(mx, 32));
    const float mnew = fmaxf(m_r, mx);
    const float corr = __expf(m_r - mnew);
    m_r = mnew;

    // P = exp(S - m), bf16-rounded; write to per-wave LDS (no barrier needed)
    float ps = 0.0f;
    #pragma unroll
    for (int st = 0; st < 4; ++st) {
      u16x4 pk;
      #pragma unroll
      for (int r = 0; r < 4; ++r) {
        const unsigned short pb = f2bf(__expf(s[st][r] - mnew));
        pk[r] = pb;
        ps += bf2f(pb);                  // denominator matches bf16 numerator
      }
      *(u16x4*)(&Pw[w][fr][st * 16 + fq * 4]) = pk;
    }
    ps += __shfl_xor(ps, 16);
    ps += __shfl_xor(ps, 32);
    l_r = l_r * corr + ps;

    // rescale O: corr lives at lane fr=q; oacc row q = fq*4+r
    #pragma unroll
    for (int r = 0; r < 4; ++r) {
      const float cr = __shfl(corr, fq * 4 + r);
      #pragma unroll
      for (int dsub = 0; dsub < 4; ++dsub) oacc[dsub][r] *= cr;
    }

    // PV: A = P (from wave-local LDS), B = V^T rows; K=32 MFMA
    #pragma unroll
    for (int k32 = 0; k32 < 2; ++k32) {
      if (k0 + k32 * 32 <= qw + 15) {    // wave-uniform causal skip
        const u16x8 pf = *(const u16x8*)(&Pw[w][fr][k32 * 32 + fq * 8]);
        #pragma unroll
        for (int dsub = 0; dsub < 4; ++dsub) {
          const u16x8 vf = *(const u16x8*)(&Vt[dsub * 16 + fr][k32 * 32 + fq * 8]);
          oacc[dsub] = mfma16(pf, vf, oacc[dsub]);
        }
      }
    }
  }

  // epilogue: 1/l lives at lane fr=q; oacc row q = fq*4+r
  const float linv_own = 1.0f / l_r;
  #pragma unroll
  for (int r = 0; r < 4; ++r) {
    const float inv = __shfl(linv_own, fq * 4 + r);
    const int qg = qw + fq * 4 + r;
    const size_t base = ((size_t)(b * TSEQ + qg)) * NSTATE + h * DHEAD;
    #pragma unroll
    for (int dsub = 0; dsub < 4; ++dsub)
      O[base + dsub * 16 + fr] = f2bf(oacc[dsub][r] * inv);
  }
}

// ---------------- launcher ----------------
extern "C" void kernel_launch(void* const* d_in, const int* in_sizes, int n_in,
                              void* d_out, int out_size, void* d_ws, size_t ws_size,
                              hipStream_t stream)
{
  (void)in_sizes; (void)n_in; (void)out_size; (void)ws_size;
  const float* x  = (const float*)d_in[0];
  // d_in[1] = mask (pure causal -1e9 tril; implemented analytically)
  const float* Wq = (const float*)d_in[2];
  const float* bq = (const float*)d_in[3];
  const float* Wk = (const float*)d_in[4];
  const float* Wv = (const float*)d_in[5];
  const float* bv = (const float*)d_in[6];
  const float* Wo = (const float*)d_in[7];
  const float* bo = (const float*)d_in[8];

  char* ws = (char*)d_ws;
  unsigned short* xb  = (unsigned short*)(ws);               // 16MB (reused for attn out)
  unsigned short* wqb = (unsigned short*)(ws + (16u << 20));
  unsigned short* wkb = wqb + (1u << 20);
  unsigned short* wvb = wkb + (1u << 20);
  unsigned short* wob = wvb + (1u << 20);
  unsigned short* qb_ = (unsigned short*)(ws + (24u << 20)); // 16MB each
  unsigned short* kb_ = (unsigned short*)(ws + (40u << 20));
  unsigned short* vb_ = (unsigned short*)(ws + (56u << 20));

  cvt_kernel<<<2048, 256, 0, stream>>>(x,  xb,  MROWS * NSTATE / 4);
  cvt_kernel<<<512,  256, 0, stream>>>(Wq, wqb, NSTATE * NSTATE / 4);
  cvt_kernel<<<512,  256, 0, stream>>>(Wk, wkb, NSTATE * NSTATE / 4);
  cvt_kernel<<<512,  256, 0, stream>>>(Wv, wvb, NSTATE * NSTATE / 4);
  cvt_kernel<<<512,  256, 0, stream>>>(Wo, wob, NSTATE * NSTATE / 4);

  const dim3 gg(NSTATE / 128, MROWS / 128);
  gemm_bt<0><<<gg, 256, 0, stream>>>(xb, wqb, bq, qb_);
  gemm_bt<1><<<gg, 256, 0, stream>>>(xb, wkb, bq, kb_);
  gemm_bt<2><<<gg, 256, 0, stream>>>(xb, wvb, bv, vb_);

  flash_attn<<<dim3(TSEQ / 64, BATCH * NHEAD), 256, 0, stream>>>(qb_, kb_, vb_, xb);

  gemm_bt<3><<<gg, 256, 0, stream>>>(xb, wob, bo, d_out);
}

// Round 3
// 282.881 us; speedup vs baseline: 1.7100x; 1.5004x over previous
//
#include <hip/hip_runtime.h>
#include <stdint.h>

#define DEVI __device__ __forceinline__

typedef float        f32x4   __attribute__((ext_vector_type(4)));
typedef float        f32x16  __attribute__((ext_vector_type(16)));
typedef __bf16       bf16x8  __attribute__((ext_vector_type(8)));
typedef unsigned short u16x8 __attribute__((ext_vector_type(8)));
typedef uint32_t     u32x4   __attribute__((ext_vector_type(4)));

static constexpr int TSEQ   = 2048;
static constexpr int NSTATE = 1024;
static constexpr int NHEAD  = 16;
static constexpr int DHEAD  = 64;
static constexpr int BATCH  = 4;
static constexpr int MROWS  = BATCH * TSEQ;              // 8192
static constexpr float SCALE = 0.35355339059327373f;     // 64^-0.25

DEVI unsigned short f2bf(float f) {
  union { float f; uint32_t u; } v; v.f = f;
  return (unsigned short)((v.u + 0x7fffu + ((v.u >> 16) & 1u)) >> 16);
}
DEVI float bf2f(unsigned short s) {
  union { uint32_t u; float f; } v; v.u = ((uint32_t)s) << 16;
  return v.f;
}

DEVI f32x4 mfma16(u16x8 a, u16x8 b, f32x4 c) {
  return __builtin_amdgcn_mfma_f32_16x16x32_bf16(
      __builtin_bit_cast(bf16x8, a), __builtin_bit_cast(bf16x8, b), c, 0, 0, 0);
}
DEVI f32x16 mfma32(u16x8 a, u16x8 b, f32x16 c) {
  return __builtin_amdgcn_mfma_f32_32x32x16_bf16(
      __builtin_bit_cast(bf16x8, a), __builtin_bit_cast(bf16x8, b), c, 0, 0, 0);
}

DEVI void gload_lds16(const void* g, void* l) {
  __builtin_amdgcn_global_load_lds(
      (const __attribute__((address_space(1))) void*)g,
      (__attribute__((address_space(3))) void*)l, 16, 0, 0);
}

// ---------------- f32 -> bf16 conversion ----------------
__global__ void cvt_kernel(const float* __restrict__ in,
                           unsigned short* __restrict__ out, int n4) {
  int i = blockIdx.x * blockDim.x + threadIdx.x;
  const int stride = gridDim.x * blockDim.x;
  for (; i < n4; i += stride) {
    const float4 f = ((const float4*)in)[i];
    ushort4 o;
    o.x = f2bf(f.x); o.y = f2bf(f.y); o.z = f2bf(f.z); o.w = f2bf(f.w);
    ((ushort4*)out)[i] = o;
  }
}

// ---------------- GEMM: C[m][n] = sum_k A[m][k] * W[n][k] (+bias, epilogue) ----
template<int MODE>
__global__ __launch_bounds__(256)
void gemm_bt(const unsigned short* __restrict__ A,
             const unsigned short* __restrict__ Bw,
             const float* __restrict__ bias,
             void* __restrict__ out)
{
  __shared__ __align__(16) unsigned short As[128 * 32];
  __shared__ __align__(16) unsigned short Bs[128 * 32];
  const int t  = threadIdx.x;
  const int l  = t & 63, w = t >> 6;
  const int fr = l & 15, fq = l >> 4;
  const int m0 = blockIdx.y * 128, n0 = blockIdx.x * 128;
  const int wm = (w & 1) * 64, wn = (w >> 1) * 64;

  f32x4 acc[4][4] = {};

  const int sr = t >> 2;
  const int sc = (t & 3) * 8;
  const unsigned short* ag = A  + (size_t)(m0 + sr) * NSTATE + sc;
  const unsigned short* bg = Bw + (size_t)(n0 + sr) * NSTATE + sc;
  unsigned short* lA0 = As + t * 8;
  unsigned short* lA1 = As + 2048 + t * 8;
  unsigned short* lB0 = Bs + t * 8;
  unsigned short* lB1 = Bs + 2048 + t * 8;

  for (int kt = 0; kt < NSTATE / 32; ++kt) {
    const int ko = kt * 32;
    gload_lds16(ag + ko,               lA0);
    gload_lds16(ag + 64 * NSTATE + ko, lA1);
    gload_lds16(bg + ko,               lB0);
    gload_lds16(bg + 64 * NSTATE + ko, lB1);
    __syncthreads();

    u16x8 a[4], b[4];
    #pragma unroll
    for (int i = 0; i < 4; ++i)
      a[i] = *(const u16x8*)(As + (wm + i * 16 + fr) * 32 + fq * 8);
    #pragma unroll
    for (int j = 0; j < 4; ++j)
      b[j] = *(const u16x8*)(Bs + (wn + j * 16 + fr) * 32 + fq * 8);
    #pragma unroll
    for (int i = 0; i < 4; ++i)
      #pragma unroll
      for (int j = 0; j < 4; ++j)
        acc[i][j] = mfma16(a[i], b[j], acc[i][j]);
    __syncthreads();
  }

  if (MODE == 3) {
    float* Co = (float*)out;
    #pragma unroll
    for (int j = 0; j < 4; ++j) {
      const int col = n0 + wn + j * 16 + fr;
      const float bj = bias[col];
      #pragma unroll
      for (int i = 0; i < 4; ++i) {
        const int row0 = m0 + wm + i * 16 + fq * 4;
        #pragma unroll
        for (int r = 0; r < 4; ++r)
          Co[(size_t)(row0 + r) * NSTATE + col] = acc[i][j][r] + bj;
      }
    }
  } else {
    unsigned short* Cq = (unsigned short*)out;
    const int h = (n0 + wn) >> 6;
    #pragma unroll
    for (int j = 0; j < 4; ++j) {
      const int d = j * 16 + fr;
      const float bj = (MODE == 1) ? 0.0f : bias[n0 + wn + d];
      #pragma unroll
      for (int i = 0; i < 4; ++i) {
        #pragma unroll
        for (int r = 0; r < 4; ++r) {
          const int row = m0 + wm + i * 16 + fq * 4 + r;
          const int bb = row >> 11, tt = row & (TSEQ - 1);
          float v = acc[i][j][r];
          if (MODE == 0)      v = (v + bj) * SCALE;
          else if (MODE == 1) v = v * SCALE;
          else                v = v + bj;
          Cq[(((size_t)(bb * NHEAD + h)) * TSEQ + tt) * DHEAD + d] = f2bf(v);
        }
      }
    }
  }
}

// ---------------- flash attention: 8 waves x 32 q-rows, 32x32x16 MFMA --------
// grid (8, 64), block 512. KVBLK=64, K/V double-buffered in LDS (XOR-swizzled).
// S^T = mfma32(K, Q): C col = q = lane&31, row = k-pattern. Per-lane softmax
// state (1 q-row/lane); P exchanged lane<->lane^32 in-register; O^T = V^T P^T.
__global__ __launch_bounds__(512)
void flash_attn(const unsigned short* __restrict__ Qg,
                const unsigned short* __restrict__ Kg,
                const unsigned short* __restrict__ Vg,
                unsigned short* __restrict__ O)
{
  const int qb = 7 - (int)blockIdx.x;
  const int bh = blockIdx.y;
  const int b  = bh >> 4, h = bh & 15;
  const int t  = threadIdx.x, lane = t & 63, w = t >> 6;
  const int lq = lane & 31, hi = lane >> 5;
  const size_t hoff = (size_t)bh * TSEQ * DHEAD;
  const unsigned short* Qp = Qg + hoff;
  const unsigned short* Kp = Kg + hoff;
  const unsigned short* Vp = Vg + hoff;

  __shared__ __align__(16) unsigned short Kb[2][64 * 64];
  __shared__ __align__(16) unsigned short Vb[2][64 * 64];   // V^T, swizzled cols

  const int qw   = qb * 256 + w * 32;        // wave's first q-row
  const int qrow = qw + lq;                  // this lane's q-row

  u16x8 qf[4];                               // Q[qrow][16c + hi*8 .. +7]
  #pragma unroll
  for (int c = 0; c < 4; ++c)
    qf[c] = *(const u16x8*)(Qp + (size_t)qrow * DHEAD + c * 16 + hi * 8);

  f32x16 oacc[2] = {};                       // O^T: col=q(lane), rows d-pattern
  float m_r = -1e30f, l_r = 0.0f;

  // staging assignments
  const int skr = t >> 3, skg = t & 7;       // K: row t>>3, d-octet t&7 (coalesced)
  const int svk = lane,  svd = w * 8;        // V: k=lane, d-octet per wave

  const int nt = (qb + 1) * 4;

  { // prologue: stage tile 0
    const u16x8 kr = *(const u16x8*)(Kp + (size_t)skr * DHEAD + skg * 8);
    const u16x8 vr = *(const u16x8*)(Vp + (size_t)svk * DHEAD + svd);
    *(u16x8*)(&Kb[0][skr * 64 + ((skg ^ (skr & 7)) << 3)]) = kr;
    #pragma unroll
    for (int i = 0; i < 8; ++i)
      Vb[0][(svd + i) * 64 + (svk ^ (i << 3))] = vr[i];
  }
  __syncthreads();

  for (int kt = 0; kt < nt; ++kt) {
    const int k0 = kt * 64, cur = kt & 1;
    const bool pre = (kt + 1 < nt);
    u16x8 krn, vrn;
    if (pre) {                               // T14: issue next-tile loads early
      const int k0n = k0 + 64;
      krn = *(const u16x8*)(Kp + (size_t)(k0n + skr) * DHEAD + skg * 8);
      vrn = *(const u16x8*)(Vp + (size_t)(k0n + svk) * DHEAD + svd);
    }

    if (k0 < qw + 32) {                      // wave-active (not fully masked)
      // ---- QK^T: S^T[k][q], 2 x (32k) tiles, 4 K=16 chunks over D=64
      f32x16 s[2];
      #pragma unroll
      for (int t32 = 0; t32 < 2; ++t32) {
        if (k0 + t32 * 32 < qw + 32) {
          f32x16 z = {};
          #pragma unroll
          for (int c = 0; c < 4; ++c) {
            const u16x8 kf = *(const u16x8*)(
                &Kb[cur][(t32 * 32 + lq) * 64 + (((2 * c + hi) ^ (lane & 7)) << 3)]);
            z = mfma32(kf, qf[c], z);
          }
          s[t32] = z;
        } else {
          #pragma unroll
          for (int r = 0; r < 16; ++r) s[t32][r] = -1e30f;
        }
      }
      if (k0 + 63 > qw) {                    // crossing: element causal mask
        #pragma unroll
        for (int t32 = 0; t32 < 2; ++t32)
          #pragma unroll
          for (int r = 0; r < 16; ++r) {
            const int kk = k0 + t32 * 32 + (r & 3) + 8 * (r >> 2) + 4 * hi;
            if (kk > qrow) s[t32][r] = -1e30f;
          }
      }

      // ---- softmax: in-lane max + one cross-half shuffle
      float mx = s[0][0];
      #pragma unroll
      for (int r = 1; r < 16; ++r) mx = fmaxf(mx, s[0][r]);
      #pragma unroll
      for (int r = 0; r < 16; ++r) mx = fmaxf(mx, s[1][r]);
      mx = fmaxf(mx, __shfl_xor(mx, 32));

      if (__any(mx > m_r + 8.0f)) {          // T13 defer-max
        const float mnew = fmaxf(m_r, mx);
        const float corr = __expf(m_r - mnew);
        #pragma unroll
        for (int ds = 0; ds < 2; ++ds)
          #pragma unroll
          for (int r = 0; r < 16; ++r) oacc[ds][r] *= corr;
        l_r *= corr;
        m_r = mnew;
      }

      // ---- P = exp(S - m) -> bf16 pairs; l-sum from rounded values
      float ps = 0.0f;
      uint32_t pk[2][8];
      #pragma unroll
      for (int t32 = 0; t32 < 2; ++t32)
        #pragma unroll
        for (int m2 = 0; m2 < 8; ++m2) {
          const float pa = __expf(s[t32][2 * m2]     - m_r);
          const float pb = __expf(s[t32][2 * m2 + 1] - m_r);
          const unsigned short ba = f2bf(pa), bb = f2bf(pb);
          ps += bf2f(ba) + bf2f(bb);
          pk[t32][m2] = (uint32_t)ba | ((uint32_t)bb << 16);
        }
      ps += __shfl_xor(ps, 32);
      l_r += ps;

      // ---- P frags: lane<->lane^32 half exchange (B-frag: k=hi*8+j, col=q)
      uint32_t pf[2][2][4];
      #pragma unroll
      for (int t32 = 0; t32 < 2; ++t32)
        #pragma unroll
        for (int hf = 0; hf < 2; ++hf) {
          const uint32_t a0 = pk[t32][hf * 4 + 0], a1 = pk[t32][hf * 4 + 1];
          const uint32_t a2 = pk[t32][hf * 4 + 2], a3 = pk[t32][hf * 4 + 3];
          const uint32_t x0 = __shfl_xor(a0, 32), x1 = __shfl_xor(a1, 32);
          const uint32_t x2 = __shfl_xor(a2, 32), x3 = __shfl_xor(a3, 32);
          pf[t32][hf][0] = hi ? x2 : a0;
          pf[t32][hf][1] = hi ? x3 : a1;
          pf[t32][hf][2] = hi ? a2 : x0;
          pf[t32][hf][3] = hi ? a3 : x1;
        }

      // ---- PV: O^T += V^T * P^T, 4 K=16 chunks over the 64 k
      #pragma unroll
      for (int c = 0; c < 4; ++c) {
        if (k0 + 16 * c < qw + 32) {         // wave-uniform causal chunk skip
          const u32x4 pw = {pf[c >> 1][c & 1][0], pf[c >> 1][c & 1][1],
                            pf[c >> 1][c & 1][2], pf[c >> 1][c & 1][3]};
          const u16x8 pv = __builtin_bit_cast(u16x8, pw);
          #pragma unroll
          for (int ds = 0; ds < 2; ++ds) {
            const u16x8 vf = *(const u16x8*)(
                &Vb[cur][(ds * 32 + lq) * 64 + (((2 * c + hi) ^ (lq & 7)) << 3)]);
            oacc[ds] = mfma32(vf, pv, oacc[ds]);
          }
        }
      }
    }

    if (pre) {                               // write-late into the other buffer
      *(u16x8*)(&Kb[cur ^ 1][skr * 64 + ((skg ^ (skr & 7)) << 3)]) = krn;
      #pragma unroll
      for (int i = 0; i < 8; ++i)
        Vb[cur ^ 1][(svd + i) * 64 + (svk ^ (i << 3))] = vrn[i];
    }
    __syncthreads();
  }

  // ---- epilogue: O[q][d] = oacc/l, paired u32 stores
  const float inv = 1.0f / l_r;
  const size_t base = ((size_t)(b * TSEQ + qrow)) * NSTATE + h * DHEAD;
  #pragma unroll
  for (int ds = 0; ds < 2; ++ds)
    #pragma unroll
    for (int m2 = 0; m2 < 8; ++m2) {
      const int d = ds * 32 + 2 * (m2 & 1) + 8 * (m2 >> 1) + 4 * hi;
      const uint32_t pa = (uint32_t)f2bf(oacc[ds][2 * m2] * inv) |
                          ((uint32_t)f2bf(oacc[ds][2 * m2 + 1] * inv) << 16);
      *(uint32_t*)(O + base + d) = pa;
    }
}

// ---------------- launcher ----------------
extern "C" void kernel_launch(void* const* d_in, const int* in_sizes, int n_in,
                              void* d_out, int out_size, void* d_ws, size_t ws_size,
                              hipStream_t stream)
{
  (void)in_sizes; (void)n_in; (void)out_size; (void)ws_size;
  const float* x  = (const float*)d_in[0];
  const float* Wq = (const float*)d_in[2];
  const float* bq = (const float*)d_in[3];
  const float* Wk = (const float*)d_in[4];
  const float* Wv = (const float*)d_in[5];
  const float* bv = (const float*)d_in[6];
  const float* Wo = (const float*)d_in[7];
  const float* bo = (const float*)d_in[8];

  char* ws = (char*)d_ws;
  unsigned short* xb  = (unsigned short*)(ws);               // 16MB (reused for attn out)
  unsigned short* wqb = (unsigned short*)(ws + (16u << 20));
  unsigned short* wkb = wqb + (1u << 20);
  unsigned short* wvb = wkb + (1u << 20);
  unsigned short* wob = wvb + (1u << 20);
  unsigned short* qb_ = (unsigned short*)(ws + (24u << 20)); // 16MB each
  unsigned short* kb_ = (unsigned short*)(ws + (40u << 20));
  unsigned short* vb_ = (unsigned short*)(ws + (56u << 20));

  cvt_kernel<<<2048, 256, 0, stream>>>(x,  xb,  MROWS * NSTATE / 4);
  cvt_kernel<<<512,  256, 0, stream>>>(Wq, wqb, NSTATE * NSTATE / 4);
  cvt_kernel<<<512,  256, 0, stream>>>(Wk, wkb, NSTATE * NSTATE / 4);
  cvt_kernel<<<512,  256, 0, stream>>>(Wv, wvb, NSTATE * NSTATE / 4);
  cvt_kernel<<<512,  256, 0, stream>>>(Wo, wob, NSTATE * NSTATE / 4);

  const dim3 gg(NSTATE / 128, MROWS / 128);
  gemm_bt<0><<<gg, 256, 0, stream>>>(xb, wqb, bq, qb_);
  gemm_bt<1><<<gg, 256, 0, stream>>>(xb, wkb, bq, kb_);
  gemm_bt<2><<<gg, 256, 0, stream>>>(xb, wvb, bv, vb_);

  flash_attn<<<dim3(8, BATCH * NHEAD), 512, 0, stream>>>(qb_, kb_, vb_, xb);

  gemm_bt<3><<<gg, 256, 0, stream>>>(xb, wob, bo, d_out);
}

// Round 4
// 234.014 us; speedup vs baseline: 2.0671x; 1.2088x over previous
//
#include <hip/hip_runtime.h>
#include <stdint.h>

#define DEVI __device__ __forceinline__

typedef float        f32x4   __attribute__((ext_vector_type(4)));
typedef float        f32x16  __attribute__((ext_vector_type(16)));
typedef __bf16       bf16x8  __attribute__((ext_vector_type(8)));
typedef unsigned short u16x8 __attribute__((ext_vector_type(8)));
typedef uint32_t     u32x4   __attribute__((ext_vector_type(4)));

static constexpr int TSEQ   = 2048;
static constexpr int NSTATE = 1024;
static constexpr int NHEAD  = 16;
static constexpr int DHEAD  = 64;
static constexpr int BATCH  = 4;
static constexpr int MROWS  = BATCH * TSEQ;              // 8192
// Q epilogue scale: D^-0.25 * D^-0.25 * log2(e)  (whole softmax in exp2 domain)
static constexpr float QSCALE = 0.125f * 1.44269504088896340736f;
static constexpr float DEFER_THR = 8.0f * 1.44269504088896340736f;

DEVI unsigned short f2bf(float f) {
  union { float f; uint32_t u; } v; v.f = f;
  return (unsigned short)((v.u + 0x7fffu + ((v.u >> 16) & 1u)) >> 16);
}
DEVI float bf2f(unsigned short s) {
  union { uint32_t u; float f; } v; v.u = ((uint32_t)s) << 16;
  return v.f;
}

DEVI f32x4 mfma16(u16x8 a, u16x8 b, f32x4 c) {
  return __builtin_amdgcn_mfma_f32_16x16x32_bf16(
      __builtin_bit_cast(bf16x8, a), __builtin_bit_cast(bf16x8, b), c, 0, 0, 0);
}
DEVI f32x16 mfma32(u16x8 a, u16x8 b, f32x16 c) {
  return __builtin_amdgcn_mfma_f32_32x32x16_bf16(
      __builtin_bit_cast(bf16x8, a), __builtin_bit_cast(bf16x8, b), c, 0, 0, 0);
}

DEVI void gload_lds16(const void* g, void* l) {
  __builtin_amdgcn_global_load_lds(
      (const __attribute__((address_space(1))) void*)g,
      (__attribute__((address_space(3))) void*)l, 16, 0, 0);
}

// ---------------- f32 -> bf16 conversion ----------------
__global__ void cvt_kernel(const float* __restrict__ in,
                           unsigned short* __restrict__ out, int n4) {
  int i = blockIdx.x * blockDim.x + threadIdx.x;
  const int stride = gridDim.x * blockDim.x;
  for (; i < n4; i += stride) {
    const float4 f = ((const float4*)in)[i];
    ushort4 o;
    o.x = f2bf(f.x); o.y = f2bf(f.y); o.z = f2bf(f.z); o.w = f2bf(f.w);
    ((ushort4*)out)[i] = o;
  }
}

// 4 weights (1024x1024 each) in one launch
__global__ void cvt4_kernel(const float* __restrict__ w0, const float* __restrict__ w1,
                            const float* __restrict__ w2, const float* __restrict__ w3,
                            unsigned short* __restrict__ o0, unsigned short* __restrict__ o1,
                            unsigned short* __restrict__ o2, unsigned short* __restrict__ o3) {
  const int per = NSTATE * NSTATE / 4;     // float4 groups per weight
  int i = blockIdx.x * blockDim.x + threadIdx.x;
  const int stride = gridDim.x * blockDim.x;
  for (; i < 4 * per; i += stride) {
    const int wi = i / per, j = i - wi * per;
    const float* src = (wi == 0) ? w0 : (wi == 1) ? w1 : (wi == 2) ? w2 : w3;
    unsigned short* dst = (wi == 0) ? o0 : (wi == 1) ? o1 : (wi == 2) ? o2 : o3;
    const float4 f = ((const float4*)src)[j];
    ushort4 o;
    o.x = f2bf(f.x); o.y = f2bf(f.y); o.z = f2bf(f.z); o.w = f2bf(f.w);
    ((ushort4*)dst)[j] = o;
  }
}

// ---------------- GEMM: C[m][n] = sum_k A[m][k] * W[n][k] (+bias, epilogue) ----
// MODE 0: Q = (acc+bias)*QSCALE -> bf16 scatter (B,H,T,D)
// MODE 1: K = acc               -> bf16 scatter (B,H,T,D)
// MODE 2: V = acc+bias          -> bf16 scatter (B,H,T,D)
// MODE 3: O = acc+bias          -> f32 row-major [M][N]
template<int MODE>
__global__ __launch_bounds__(256)
void gemm_bt(const unsigned short* __restrict__ A,
             const unsigned short* __restrict__ Bw,
             const float* __restrict__ bias,
             void* __restrict__ out)
{
  __shared__ __align__(16) unsigned short As[128 * 32];
  __shared__ __align__(16) unsigned short Bs[128 * 32];
  const int t  = threadIdx.x;
  const int l  = t & 63, w = t >> 6;
  const int fr = l & 15, fq = l >> 4;
  const int m0 = blockIdx.y * 128, n0 = blockIdx.x * 128;
  const int wm = (w & 1) * 64, wn = (w >> 1) * 64;

  f32x4 acc[4][4] = {};

  const int sr = t >> 2;
  const int sc = (t & 3) * 8;
  const unsigned short* ag = A  + (size_t)(m0 + sr) * NSTATE + sc;
  const unsigned short* bg = Bw + (size_t)(n0 + sr) * NSTATE + sc;
  unsigned short* lA0 = As + t * 8;
  unsigned short* lA1 = As + 2048 + t * 8;
  unsigned short* lB0 = Bs + t * 8;
  unsigned short* lB1 = Bs + 2048 + t * 8;

  for (int kt = 0; kt < NSTATE / 32; ++kt) {
    const int ko = kt * 32;
    gload_lds16(ag + ko,               lA0);
    gload_lds16(ag + 64 * NSTATE + ko, lA1);
    gload_lds16(bg + ko,               lB0);
    gload_lds16(bg + 64 * NSTATE + ko, lB1);
    __syncthreads();

    u16x8 a[4], b[4];
    #pragma unroll
    for (int i = 0; i < 4; ++i)
      a[i] = *(const u16x8*)(As + (wm + i * 16 + fr) * 32 + fq * 8);
    #pragma unroll
    for (int j = 0; j < 4; ++j)
      b[j] = *(const u16x8*)(Bs + (wn + j * 16 + fr) * 32 + fq * 8);
    #pragma unroll
    for (int i = 0; i < 4; ++i)
      #pragma unroll
      for (int j = 0; j < 4; ++j)
        acc[i][j] = mfma16(a[i], b[j], acc[i][j]);
    __syncthreads();
  }

  if (MODE == 3) {
    float* Co = (float*)out;
    #pragma unroll
    for (int j = 0; j < 4; ++j) {
      const int col = n0 + wn + j * 16 + fr;
      const float bj = bias[col];
      #pragma unroll
      for (int i = 0; i < 4; ++i) {
        const int row0 = m0 + wm + i * 16 + fq * 4;
        #pragma unroll
        for (int r = 0; r < 4; ++r)
          Co[(size_t)(row0 + r) * NSTATE + col] = acc[i][j][r] + bj;
      }
    }
  } else {
    unsigned short* Cq = (unsigned short*)out;
    const int h = (n0 + wn) >> 6;
    #pragma unroll
    for (int j = 0; j < 4; ++j) {
      const int d = j * 16 + fr;
      const float bj = (MODE == 1) ? 0.0f : bias[n0 + wn + d];
      #pragma unroll
      for (int i = 0; i < 4; ++i) {
        #pragma unroll
        for (int r = 0; r < 4; ++r) {
          const int row = m0 + wm + i * 16 + fq * 4 + r;
          const int bb = row >> 11, tt = row & (TSEQ - 1);
          float v = acc[i][j][r];
          if (MODE == 0)      v = (v + bj) * QSCALE;
          else if (MODE == 1) v = v;
          else                v = v + bj;
          Cq[(((size_t)(bb * NHEAD + h)) * TSEQ + tt) * DHEAD + d] = f2bf(v);
        }
      }
    }
  }
}

// ---------------- flash attention: 4 waves x 32 q-rows, 32x32x16 MFMA --------
// grid (64 heads, 16 q-tiles), block 256 = 4 waves; qb = 15 - y (longest first).
// KVBLK=64, K/V double-buffered LDS (XOR-swizzled), T14 early-issue staging.
// S^T = mfma32(K, Q); per-lane softmax state in exp2 domain; P exchanged
// lane<->lane^32 in-register; O^T = V^T P^T.
__global__ __launch_bounds__(256)
void flash_attn(const unsigned short* __restrict__ Qg,
                const unsigned short* __restrict__ Kg,
                const unsigned short* __restrict__ Vg,
                unsigned short* __restrict__ O)
{
  const int bh = blockIdx.x;
  const int qb = 15 - (int)blockIdx.y;
  const int b  = bh >> 4, h = bh & 15;
  const int t  = threadIdx.x, lane = t & 63, w = t >> 6;   // w: 0..3
  const int lq = lane & 31, hi = lane >> 5;
  const size_t hoff = (size_t)bh * TSEQ * DHEAD;
  const unsigned short* Qp = Qg + hoff;
  const unsigned short* Kp = Kg + hoff;
  const unsigned short* Vp = Vg + hoff;

  __shared__ __align__(16) unsigned short Kb[2][64 * 64];
  __shared__ __align__(16) unsigned short Vb[2][64 * 64];   // V^T, swizzled cols

  const int qw   = qb * 128 + w * 32;        // wave's first q-row
  const int qrow = qw + lq;                  // this lane's q-row

  u16x8 qf[4];                               // Q[qrow][16c + hi*8 .. +7]
  #pragma unroll
  for (int c = 0; c < 4; ++c)
    qf[c] = *(const u16x8*)(Qp + (size_t)qrow * DHEAD + c * 16 + hi * 8);

  f32x16 oacc[2] = {};                       // O^T: col=q(lane), rows d-pattern
  float m_r = -1e30f, l_r = 0.0f;            // exp2-domain softmax state

  // staging assignments (256 threads)
  const int skr = t >> 2, skg = t & 3;       // K: row skr, 32B chunk skg
  const int svk = lane,  svd = w * 16;       // V: k=lane, 16 d-cols per wave

  const int nt = (qb + 1) * 2;

  { // prologue: stage tile 0
    const u16x8 kr0 = *(const u16x8*)(Kp + (size_t)skr * DHEAD + skg * 16);
    const u16x8 kr1 = *(const u16x8*)(Kp + (size_t)skr * DHEAD + skg * 16 + 8);
    const u16x8 vr0 = *(const u16x8*)(Vp + (size_t)svk * DHEAD + svd);
    const u16x8 vr1 = *(const u16x8*)(Vp + (size_t)svk * DHEAD + svd + 8);
    *(u16x8*)(&Kb[0][skr * 64 + (((skg * 2)     ^ (skr & 7)) << 3)]) = kr0;
    *(u16x8*)(&Kb[0][skr * 64 + (((skg * 2 + 1) ^ (skr & 7)) << 3)]) = kr1;
    #pragma unroll
    for (int i = 0; i < 8; ++i)
      Vb[0][(svd + i) * 64 + (svk ^ (i << 3))] = vr0[i];
    #pragma unroll
    for (int i = 0; i < 8; ++i)
      Vb[0][(svd + 8 + i) * 64 + (svk ^ (i << 3))] = vr1[i];
  }
  __syncthreads();

  for (int kt = 0; kt < nt; ++kt) {
    const int k0 = kt * 64, cur = kt & 1;
    const bool pre = (kt + 1 < nt);
    u16x8 krn0, krn1, vrn0, vrn1;
    if (pre) {                               // T14: issue next-tile loads early
      const int k0n = k0 + 64;
      krn0 = *(const u16x8*)(Kp + (size_t)(k0n + skr) * DHEAD + skg * 16);
      krn1 = *(const u16x8*)(Kp + (size_t)(k0n + skr) * DHEAD + skg * 16 + 8);
      vrn0 = *(const u16x8*)(Vp + (size_t)(k0n + svk) * DHEAD + svd);
      vrn1 = *(const u16x8*)(Vp + (size_t)(k0n + svk) * DHEAD + svd + 8);
    }

    if (k0 < qw + 32) {                      // wave-active (not fully masked)
      // ---- QK^T: S^T[k][q], 2 x (32k) tiles, 4 K=16 chunks over D=64
      f32x16 s[2];
      #pragma unroll
      for (int t32 = 0; t32 < 2; ++t32) {
        if (k0 + t32 * 32 < qw + 32) {
          f32x16 z = {};
          #pragma unroll
          for (int c = 0; c < 4; ++c) {
            const u16x8 kf = *(const u16x8*)(
                &Kb[cur][(t32 * 32 + lq) * 64 + (((2 * c + hi) ^ (lane & 7)) << 3)]);
            z = mfma32(kf, qf[c], z);
          }
          s[t32] = z;
        } else {
          #pragma unroll
          for (int r = 0; r < 16; ++r) s[t32][r] = -1e30f;
        }
      }
      if (k0 + 63 > qw) {                    // crossing: element causal mask
        #pragma unroll
        for (int t32 = 0; t32 < 2; ++t32)
          #pragma unroll
          for (int r = 0; r < 16; ++r) {
            const int kk = k0 + t32 * 32 + (r & 3) + 8 * (r >> 2) + 4 * hi;
            if (kk > qrow) s[t32][r] = -1e30f;
          }
      }

      // ---- softmax max: in-lane + one cross-half shuffle
      float mx = s[0][0];
      #pragma unroll
      for (int r = 1; r < 16; ++r) mx = fmaxf(mx, s[0][r]);
      #pragma unroll
      for (int r = 0; r < 16; ++r) mx = fmaxf(mx, s[1][r]);
      mx = fmaxf(mx, __shfl_xor(mx, 32));

      if (__any(mx > m_r + DEFER_THR)) {     // T13 defer-max
        const float mnew = fmaxf(m_r, mx);
        const float corr = exp2f(m_r - mnew);
        #pragma unroll
        for (int ds = 0; ds < 2; ++ds)
          #pragma unroll
          for (int r = 0; r < 16; ++r) oacc[ds][r] *= corr;
        l_r *= corr;
        m_r = mnew;
      }

      // ---- P = exp2(S - m) -> bf16 pairs; l-sum from rounded values
      float ps = 0.0f;
      uint32_t pk[2][8];
      #pragma unroll
      for (int t32 = 0; t32 < 2; ++t32)
        #pragma unroll
        for (int m2 = 0; m2 < 8; ++m2) {
          const float pa = exp2f(s[t32][2 * m2]     - m_r);
          const float pb = exp2f(s[t32][2 * m2 + 1] - m_r);
          const unsigned short ba = f2bf(pa), bb = f2bf(pb);
          ps += bf2f(ba) + bf2f(bb);
          pk[t32][m2] = (uint32_t)ba | ((uint32_t)bb << 16);
        }
      ps += __shfl_xor(ps, 32);
      l_r += ps;

      // ---- P frags: lane<->lane^32 half exchange (B-frag: k=hi*8+j, col=q)
      uint32_t pf[2][2][4];
      #pragma unroll
      for (int t32 = 0; t32 < 2; ++t32)
        #pragma unroll
        for (int hf = 0; hf < 2; ++hf) {
          const uint32_t a0 = pk[t32][hf * 4 + 0], a1 = pk[t32][hf * 4 + 1];
          const uint32_t a2 = pk[t32][hf * 4 + 2], a3 = pk[t32][hf * 4 + 3];
          const uint32_t x0 = __shfl_xor(a0, 32), x1 = __shfl_xor(a1, 32);
          const uint32_t x2 = __shfl_xor(a2, 32), x3 = __shfl_xor(a3, 32);
          pf[t32][hf][0] = hi ? x2 : a0;
          pf[t32][hf][1] = hi ? x3 : a1;
          pf[t32][hf][2] = hi ? a2 : x0;
          pf[t32][hf][3] = hi ? a3 : x1;
        }

      // ---- PV: O^T += V^T * P^T, 4 K=16 chunks over the 64 k
      #pragma unroll
      for (int c = 0; c < 4; ++c) {
        if (k0 + 16 * c < qw + 32) {         // wave-uniform causal chunk skip
          const u32x4 pw = {pf[c >> 1][c & 1][0], pf[c >> 1][c & 1][1],
                            pf[c >> 1][c & 1][2], pf[c >> 1][c & 1][3]};
          const u16x8 pv = __builtin_bit_cast(u16x8, pw);
          #pragma unroll
          for (int ds = 0; ds < 2; ++ds) {
            const u16x8 vf = *(const u16x8*)(
                &Vb[cur][(ds * 32 + lq) * 64 + (((2 * c + hi) ^ (lq & 7)) << 3)]);
            oacc[ds] = mfma32(vf, pv, oacc[ds]);
          }
        }
      }
    }

    if (pre) {                               // write-late into the other buffer
      *(u16x8*)(&Kb[cur ^ 1][skr * 64 + (((skg * 2)     ^ (skr & 7)) << 3)]) = krn0;
      *(u16x8*)(&Kb[cur ^ 1][skr * 64 + (((skg * 2 + 1) ^ (skr & 7)) << 3)]) = krn1;
      #pragma unroll
      for (int i = 0; i < 8; ++i)
        Vb[cur ^ 1][(svd + i) * 64 + (svk ^ (i << 3))] = vrn0[i];
      #pragma unroll
      for (int i = 0; i < 8; ++i)
        Vb[cur ^ 1][(svd + 8 + i) * 64 + (svk ^ (i << 3))] = vrn1[i];
    }
    __syncthreads();
  }

  // ---- epilogue: O[q][d] = oacc/l, paired u32 stores
  const float inv = 1.0f / l_r;
  const size_t base = ((size_t)(b * TSEQ + qrow)) * NSTATE + h * DHEAD;
  #pragma unroll
  for (int ds = 0; ds < 2; ++ds)
    #pragma unroll
    for (int m2 = 0; m2 < 8; ++m2) {
      const int d = ds * 32 + 2 * (m2 & 1) + 8 * (m2 >> 1) + 4 * hi;
      const uint32_t pa = (uint32_t)f2bf(oacc[ds][2 * m2] * inv) |
                          ((uint32_t)f2bf(oacc[ds][2 * m2 + 1] * inv) << 16);
      *(uint32_t*)(O + base + d) = pa;
    }
}

// ---------------- launcher ----------------
extern "C" void kernel_launch(void* const* d_in, const int* in_sizes, int n_in,
                              void* d_out, int out_size, void* d_ws, size_t ws_size,
                              hipStream_t stream)
{
  (void)in_sizes; (void)n_in; (void)out_size; (void)ws_size;
  const float* x  = (const float*)d_in[0];
  const float* Wq = (const float*)d_in[2];
  const float* bq = (const float*)d_in[3];
  const float* Wk = (const float*)d_in[4];
  const float* Wv = (const float*)d_in[5];
  const float* bv = (const float*)d_in[6];
  const float* Wo = (const float*)d_in[7];
  const float* bo = (const float*)d_in[8];

  char* ws = (char*)d_ws;
  unsigned short* xb  = (unsigned short*)(ws);               // 16MB (reused for attn out)
  unsigned short* wqb = (unsigned short*)(ws + (16u << 20));
  unsigned short* wkb = wqb + (1u << 20);
  unsigned short* wvb = wkb + (1u << 20);
  unsigned short* wob = wvb + (1u << 20);
  unsigned short* qb_ = (unsigned short*)(ws + (24u << 20)); // 16MB each
  unsigned short* kb_ = (unsigned short*)(ws + (40u << 20));
  unsigned short* vb_ = (unsigned short*)(ws + (56u << 20));

  cvt_kernel<<<2048, 256, 0, stream>>>(x,  xb,  MROWS * NSTATE / 4);
  cvt4_kernel<<<2048, 256, 0, stream>>>(Wq, Wk, Wv, Wo, wqb, wkb, wvb, wob);

  const dim3 gg(NSTATE / 128, MROWS / 128);
  gemm_bt<0><<<gg, 256, 0, stream>>>(xb, wqb, bq, qb_);
  gemm_bt<1><<<gg, 256, 0, stream>>>(xb, wkb, bq, kb_);
  gemm_bt<2><<<gg, 256, 0, stream>>>(xb, wvb, bv, vb_);

  flash_attn<<<dim3(BATCH * NHEAD, 16), 256, 0, stream>>>(qb_, kb_, vb_, xb);

  gemm_bt<3><<<gg, 256, 0, stream>>>(xb, wob, bo, d_out);
}

// Round 5
// 199.250 us; speedup vs baseline: 2.4277x; 1.1745x over previous
//
#include <hip/hip_runtime.h>
#include <stdint.h>

#define DEVI __device__ __forceinline__

typedef float        f32x4   __attribute__((ext_vector_type(4)));
typedef float        f32x16  __attribute__((ext_vector_type(16)));
typedef __bf16       bf16x8  __attribute__((ext_vector_type(8)));
typedef unsigned short u16x8 __attribute__((ext_vector_type(8)));
typedef uint32_t     u32x2   __attribute__((ext_vector_type(2)));
typedef uint32_t     u32x4   __attribute__((ext_vector_type(4)));

static constexpr int TSEQ   = 2048;
static constexpr int NSTATE = 1024;
static constexpr int NHEAD  = 16;
static constexpr int DHEAD  = 64;
static constexpr int BATCH  = 4;
static constexpr int MROWS  = BATCH * TSEQ;              // 8192
// Q epilogue scale: D^-0.5 * log2(e)  (whole softmax in exp2 domain)
static constexpr float QSCALE = 0.125f * 1.44269504088896340736f;
static constexpr float DEFER_THR = 8.0f * 1.44269504088896340736f;

DEVI unsigned short f2bf(float f) {
  union { float f; uint32_t u; } v; v.f = f;
  return (unsigned short)((v.u + 0x7fffu + ((v.u >> 16) & 1u)) >> 16);
}

DEVI uint32_t cvt_pk_bf16(float lo, float hi) {   // packs {lo,hi} -> 2xbf16 (RNE)
  uint32_t r;
  asm("v_cvt_pk_bf16_f32 %0, %1, %2" : "=v"(r) : "v"(lo), "v"(hi));
  return r;
}

DEVI f32x4 mfma16(u16x8 a, u16x8 b, f32x4 c) {
  return __builtin_amdgcn_mfma_f32_16x16x32_bf16(
      __builtin_bit_cast(bf16x8, a), __builtin_bit_cast(bf16x8, b), c, 0, 0, 0);
}
DEVI f32x16 mfma32(u16x8 a, u16x8 b, f32x16 c) {
  return __builtin_amdgcn_mfma_f32_32x32x16_bf16(
      __builtin_bit_cast(bf16x8, a), __builtin_bit_cast(bf16x8, b), c, 0, 0, 0);
}

DEVI void gload_lds16(const void* g, void* l) {
  __builtin_amdgcn_global_load_lds(
      (const __attribute__((address_space(1))) void*)g,
      (__attribute__((address_space(3))) void*)l, 16, 0, 0);
}

// ---------------- f32 -> bf16 conversion ----------------
__global__ void cvt_kernel(const float* __restrict__ in,
                           unsigned short* __restrict__ out, int n4) {
  int i = blockIdx.x * blockDim.x + threadIdx.x;
  const int stride = gridDim.x * blockDim.x;
  for (; i < n4; i += stride) {
    const float4 f = ((const float4*)in)[i];
    ushort4 o;
    o.x = f2bf(f.x); o.y = f2bf(f.y); o.z = f2bf(f.z); o.w = f2bf(f.w);
    ((ushort4*)out)[i] = o;
  }
}

// 4 weights (1024x1024 each) in one launch
__global__ void cvt4_kernel(const float* __restrict__ w0, const float* __restrict__ w1,
                            const float* __restrict__ w2, const float* __restrict__ w3,
                            unsigned short* __restrict__ o0, unsigned short* __restrict__ o1,
                            unsigned short* __restrict__ o2, unsigned short* __restrict__ o3) {
  const int per = NSTATE * NSTATE / 4;
  int i = blockIdx.x * blockDim.x + threadIdx.x;
  const int stride = gridDim.x * blockDim.x;
  for (; i < 4 * per; i += stride) {
    const int wi = i / per, j = i - wi * per;
    const float* src = (wi == 0) ? w0 : (wi == 1) ? w1 : (wi == 2) ? w2 : w3;
    unsigned short* dst = (wi == 0) ? o0 : (wi == 1) ? o1 : (wi == 2) ? o2 : o3;
    const float4 f = ((const float4*)src)[j];
    ushort4 o;
    o.x = f2bf(f.x); o.y = f2bf(f.y); o.z = f2bf(f.z); o.w = f2bf(f.w);
    ((ushort4*)dst)[j] = o;
  }
}

// ---------------- fused QKV GEMM: grid (24, 64); x -> {weight, n-tile} --------
// wi 0: Q = (acc+bq)*QSCALE ; wi 1: K = acc ; wi 2: V = acc+bv
// outputs scattered to (B,H,T,D) bf16; weight/out buffers contiguous.
__global__ __launch_bounds__(256)
void gemm_qkv(const unsigned short* __restrict__ A,
              const unsigned short* __restrict__ Wqkv,
              const float* __restrict__ bq, const float* __restrict__ bv,
              unsigned short* __restrict__ Oqkv)
{
  __shared__ __align__(16) unsigned short As[128 * 32];
  __shared__ __align__(16) unsigned short Bs[128 * 32];
  const int t  = threadIdx.x;
  const int l  = t & 63, w = t >> 6;
  const int fr = l & 15, fq = l >> 4;
  const int wi = blockIdx.x >> 3;
  const int n0 = (blockIdx.x & 7) * 128;
  const int m0 = blockIdx.y * 128;
  const int wm = (w & 1) * 64, wn = (w >> 1) * 64;
  const unsigned short* Bw = Wqkv + (size_t)wi * (1u << 20);
  unsigned short* Cq = Oqkv + (size_t)wi * (8u << 20);

  f32x4 acc[4][4] = {};

  const int sr = t >> 2;
  const int sc = (t & 3) * 8;
  const unsigned short* ag = A  + (size_t)(m0 + sr) * NSTATE + sc;
  const unsigned short* bg = Bw + (size_t)(n0 + sr) * NSTATE + sc;
  unsigned short* lA0 = As + t * 8;
  unsigned short* lA1 = As + 2048 + t * 8;
  unsigned short* lB0 = Bs + t * 8;
  unsigned short* lB1 = Bs + 2048 + t * 8;

  for (int kt = 0; kt < NSTATE / 32; ++kt) {
    const int ko = kt * 32;
    gload_lds16(ag + ko,               lA0);
    gload_lds16(ag + 64 * NSTATE + ko, lA1);
    gload_lds16(bg + ko,               lB0);
    gload_lds16(bg + 64 * NSTATE + ko, lB1);
    __syncthreads();

    u16x8 a[4], b[4];
    #pragma unroll
    for (int i = 0; i < 4; ++i)
      a[i] = *(const u16x8*)(As + (wm + i * 16 + fr) * 32 + fq * 8);
    #pragma unroll
    for (int j = 0; j < 4; ++j)
      b[j] = *(const u16x8*)(Bs + (wn + j * 16 + fr) * 32 + fq * 8);
    #pragma unroll
    for (int i = 0; i < 4; ++i)
      #pragma unroll
      for (int j = 0; j < 4; ++j)
        acc[i][j] = mfma16(a[i], b[j], acc[i][j]);
    __syncthreads();
  }

  const int h = (n0 + wn) >> 6;
  #pragma unroll
  for (int j = 0; j < 4; ++j) {
    const int d = j * 16 + fr;
    const float bj = (wi == 1) ? 0.0f
                   : ((wi == 0) ? bq[n0 + wn + d] : bv[n0 + wn + d]);
    #pragma unroll
    for (int i = 0; i < 4; ++i) {
      #pragma unroll
      for (int r = 0; r < 4; ++r) {
        const int row = m0 + wm + i * 16 + fq * 4 + r;
        const int bb = row >> 11, tt = row & (TSEQ - 1);
        float v = acc[i][j][r] + bj;
        if (wi == 0) v *= QSCALE;
        Cq[(((size_t)(bb * NHEAD + h)) * TSEQ + tt) * DHEAD + d] = f2bf(v);
      }
    }
  }
}

// ---------------- output projection GEMM: C = A W^T + bo (f32 out) ----------
__global__ __launch_bounds__(256)
void gemm_out(const unsigned short* __restrict__ A,
              const unsigned short* __restrict__ Bw,
              const float* __restrict__ bias,
              float* __restrict__ Co)
{
  __shared__ __align__(16) unsigned short As[128 * 32];
  __shared__ __align__(16) unsigned short Bs[128 * 32];
  const int t  = threadIdx.x;
  const int l  = t & 63, w = t >> 6;
  const int fr = l & 15, fq = l >> 4;
  const int m0 = blockIdx.y * 128, n0 = blockIdx.x * 128;
  const int wm = (w & 1) * 64, wn = (w >> 1) * 64;

  f32x4 acc[4][4] = {};

  const int sr = t >> 2;
  const int sc = (t & 3) * 8;
  const unsigned short* ag = A  + (size_t)(m0 + sr) * NSTATE + sc;
  const unsigned short* bg = Bw + (size_t)(n0 + sr) * NSTATE + sc;
  unsigned short* lA0 = As + t * 8;
  unsigned short* lA1 = As + 2048 + t * 8;
  unsigned short* lB0 = Bs + t * 8;
  unsigned short* lB1 = Bs + 2048 + t * 8;

  for (int kt = 0; kt < NSTATE / 32; ++kt) {
    const int ko = kt * 32;
    gload_lds16(ag + ko,               lA0);
    gload_lds16(ag + 64 * NSTATE + ko, lA1);
    gload_lds16(bg + ko,               lB0);
    gload_lds16(bg + 64 * NSTATE + ko, lB1);
    __syncthreads();

    u16x8 a[4], b[4];
    #pragma unroll
    for (int i = 0; i < 4; ++i)
      a[i] = *(const u16x8*)(As + (wm + i * 16 + fr) * 32 + fq * 8);
    #pragma unroll
    for (int j = 0; j < 4; ++j)
      b[j] = *(const u16x8*)(Bs + (wn + j * 16 + fr) * 32 + fq * 8);
    #pragma unroll
    for (int i = 0; i < 4; ++i)
      #pragma unroll
      for (int j = 0; j < 4; ++j)
        acc[i][j] = mfma16(a[i], b[j], acc[i][j]);
    __syncthreads();
  }

  #pragma unroll
  for (int j = 0; j < 4; ++j) {
    const int col = n0 + wn + j * 16 + fr;
    const float bj = bias[col];
    #pragma unroll
    for (int i = 0; i < 4; ++i) {
      const int row0 = m0 + wm + i * 16 + fq * 4;
      #pragma unroll
      for (int r = 0; r < 4; ++r)
        Co[(size_t)(row0 + r) * NSTATE + col] = acc[i][j][r] + bj;
    }
  }
}

// ---------------- flash attention: 4 waves x 32 q-rows, 32x32x16 MFMA --------
// grid (64 heads, 16 q-tiles), block 256; qb = 15 - y (longest first).
// KVBLK=64, K/V double-buffered LDS (16B-XOR swizzle), T14 early-issue staging.
// S^T = mfma32(K, Q); exp2-domain softmax; cvt_pk + permlane32_swap for P.
__global__ __launch_bounds__(256)
void flash_attn(const unsigned short* __restrict__ Qg,
                const unsigned short* __restrict__ Kg,
                const unsigned short* __restrict__ Vg,
                unsigned short* __restrict__ O)
{
  const int bh = blockIdx.x;
  const int qb = 15 - (int)blockIdx.y;
  const int b  = bh >> 4, h = bh & 15;
  const int t  = threadIdx.x, lane = t & 63, w = t >> 6;   // w: 0..3
  const int lq = lane & 31, hi = lane >> 5;
  const size_t hoff = (size_t)bh * TSEQ * DHEAD;
  const unsigned short* Qp = Qg + hoff;
  const unsigned short* Kp = Kg + hoff;
  const unsigned short* Vp = Vg + hoff;

  __shared__ __align__(16) unsigned short Kb[2][64 * 64];
  __shared__ __align__(16) unsigned short Vb[2][64 * 64];   // V^T, swizzled octets

  const int qw   = qb * 128 + w * 32;        // wave's first q-row
  const int qrow = qw + lq;                  // this lane's q-row

  u16x8 qf[4];                               // Q[qrow][16c + hi*8 .. +7]
  #pragma unroll
  for (int c = 0; c < 4; ++c)
    qf[c] = *(const u16x8*)(Qp + (size_t)qrow * DHEAD + c * 16 + hi * 8);

  f32x16 oacc[2] = {};                       // O^T: col=q(lane), rows d-pattern
  float m_r = -1e30f, l_r = 0.0f;            // exp2-domain softmax state

  // staging assignments (256 threads)
  const int skr = t >> 2, skg = t & 3;       // K: row skr, 32B chunk skg
  const int svk2 = (t & 31) * 2;             // V: two adjacent k per thread
  const int svd  = (t >> 5) * 8;             // 8 d's per thread

  const int nt = (qb + 1) * 2;

  { // prologue: stage tile 0
    const u16x8 kr0 = *(const u16x8*)(Kp + (size_t)skr * DHEAD + skg * 16);
    const u16x8 kr1 = *(const u16x8*)(Kp + (size_t)skr * DHEAD + skg * 16 + 8);
    const u16x8 va  = *(const u16x8*)(Vp + (size_t)svk2 * DHEAD + svd);
    const u16x8 vb  = *(const u16x8*)(Vp + (size_t)(svk2 + 1) * DHEAD + svd);
    *(u16x8*)(&Kb[0][skr * 64 + (((skg * 2)     ^ (skr & 7)) << 3)]) = kr0;
    *(u16x8*)(&Kb[0][skr * 64 + (((skg * 2 + 1) ^ (skr & 7)) << 3)]) = kr1;
    #pragma unroll
    for (int i = 0; i < 8; ++i)
      *(uint32_t*)(&Vb[0][(svd + i) * 64 + (svk2 ^ (i << 3))]) =
          (uint32_t)va[i] | ((uint32_t)vb[i] << 16);
  }
  __syncthreads();

  for (int kt = 0; kt < nt; ++kt) {
    const int k0 = kt * 64, cur = kt & 1;
    const bool pre = (kt + 1 < nt);
    u16x8 krn0, krn1, van, vbn;
    if (pre) {                               // T14: issue next-tile loads early
      const int k0n = k0 + 64;
      krn0 = *(const u16x8*)(Kp + (size_t)(k0n + skr) * DHEAD + skg * 16);
      krn1 = *(const u16x8*)(Kp + (size_t)(k0n + skr) * DHEAD + skg * 16 + 8);
      van  = *(const u16x8*)(Vp + (size_t)(k0n + svk2) * DHEAD + svd);
      vbn  = *(const u16x8*)(Vp + (size_t)(k0n + svk2 + 1) * DHEAD + svd);
    }

    if (k0 < qw + 32) {                      // wave-active (not fully masked)
      // ---- QK^T: S^T[k][q], 2 x (32k) tiles, 4 K=16 chunks over D=64
      f32x16 s[2];
      __builtin_amdgcn_s_setprio(1);
      #pragma unroll
      for (int t32 = 0; t32 < 2; ++t32) {
        if (k0 + t32 * 32 < qw + 32) {
          f32x16 z = {};
          #pragma unroll
          for (int c = 0; c < 4; ++c) {
            const u16x8 kf = *(const u16x8*)(
                &Kb[cur][(t32 * 32 + lq) * 64 + (((2 * c + hi) ^ (lane & 7)) << 3)]);
            z = mfma32(kf, qf[c], z);
          }
          s[t32] = z;
        } else {
          #pragma unroll
          for (int r = 0; r < 16; ++r) s[t32][r] = -1e30f;
        }
      }
      __builtin_amdgcn_s_setprio(0);
      if (k0 + 63 > qw) {                    // crossing: element causal mask
        #pragma unroll
        for (int t32 = 0; t32 < 2; ++t32)
          #pragma unroll
          for (int r = 0; r < 16; ++r) {
            const int kk = k0 + t32 * 32 + (r & 3) + 8 * (r >> 2) + 4 * hi;
            if (kk > qrow) s[t32][r] = -1e30f;
          }
      }

      // ---- softmax max: max3 tree + one cross-half shuffle
      float mx = fmaxf(s[0][14], s[0][15]);
      #pragma unroll
      for (int r = 0; r < 14; r += 2) mx = fmaxf(fmaxf(mx, s[0][r]), s[0][r + 1]);
      #pragma unroll
      for (int r = 0; r < 16; r += 2) mx = fmaxf(fmaxf(mx, s[1][r]), s[1][r + 1]);
      mx = fmaxf(mx, __shfl_xor(mx, 32));

      if (__any(mx > m_r + DEFER_THR)) {     // T13 defer-max
        const float mnew = fmaxf(m_r, mx);
        const float corr = exp2f(m_r - mnew);
        #pragma unroll
        for (int ds = 0; ds < 2; ++ds)
          #pragma unroll
          for (int r = 0; r < 16; ++r) oacc[ds][r] *= corr;
        l_r *= corr;
        m_r = mnew;
      }

      // ---- P = exp2(S - m): cvt_pk packing; l-sum in f32 (pre-rounding)
      float ps = 0.0f;
      uint32_t pk[2][8];
      #pragma unroll
      for (int t32 = 0; t32 < 2; ++t32)
        #pragma unroll
        for (int m2 = 0; m2 < 8; ++m2) {
          const float pa = exp2f(s[t32][2 * m2]     - m_r);
          const float pb = exp2f(s[t32][2 * m2 + 1] - m_r);
          ps += pa + pb;
          pk[t32][m2] = cvt_pk_bf16(pa, pb);
        }
      ps += __shfl_xor(ps, 32);
      l_r += ps;

      // ---- P frags: half-exchange via permlane32_swap (T12)
      uint32_t pf[2][2][4];
      #pragma unroll
      for (int t32 = 0; t32 < 2; ++t32)
        #pragma unroll
        for (int hf = 0; hf < 2; ++hf) {
          const u32x2 r02 = __builtin_amdgcn_permlane32_swap(
              pk[t32][hf * 4 + 0], pk[t32][hf * 4 + 2], false, false);
          const u32x2 r13 = __builtin_amdgcn_permlane32_swap(
              pk[t32][hf * 4 + 1], pk[t32][hf * 4 + 3], false, false);
          pf[t32][hf][0] = r02.x; pf[t32][hf][2] = r02.y;
          pf[t32][hf][1] = r13.x; pf[t32][hf][3] = r13.y;
        }

      // ---- PV: O^T += V^T * P^T, 4 K=16 chunks over the 64 k
      __builtin_amdgcn_s_setprio(1);
      #pragma unroll
      for (int c = 0; c < 4; ++c) {
        if (k0 + 16 * c < qw + 32) {         // wave-uniform causal chunk skip
          const u32x4 pw = {pf[c >> 1][c & 1][0], pf[c >> 1][c & 1][1],
                            pf[c >> 1][c & 1][2], pf[c >> 1][c & 1][3]};
          const u16x8 pv = __builtin_bit_cast(u16x8, pw);
          #pragma unroll
          for (int ds = 0; ds < 2; ++ds) {
            const u16x8 vf = *(const u16x8*)(
                &Vb[cur][(ds * 32 + lq) * 64 + (((2 * c + hi) ^ (lq & 7)) << 3)]);
            oacc[ds] = mfma32(vf, pv, oacc[ds]);
          }
        }
      }
      __builtin_amdgcn_s_setprio(0);
    }

    if (pre) {                               // write-late into the other buffer
      *(u16x8*)(&Kb[cur ^ 1][skr * 64 + (((skg * 2)     ^ (skr & 7)) << 3)]) = krn0;
      *(u16x8*)(&Kb[cur ^ 1][skr * 64 + (((skg * 2 + 1) ^ (skr & 7)) << 3)]) = krn1;
      #pragma unroll
      for (int i = 0; i < 8; ++i)
        *(uint32_t*)(&Vb[cur ^ 1][(svd + i) * 64 + (svk2 ^ (i << 3))]) =
            (uint32_t)van[i] | ((uint32_t)vbn[i] << 16);
    }
    __syncthreads();
  }

  // ---- epilogue: O[q][d] = oacc/l, paired u32 stores
  const float inv = 1.0f / l_r;
  const size_t base = ((size_t)(b * TSEQ + qrow)) * NSTATE + h * DHEAD;
  #pragma unroll
  for (int ds = 0; ds < 2; ++ds)
    #pragma unroll
    for (int m2 = 0; m2 < 8; ++m2) {
      const int d = ds * 32 + 2 * (m2 & 1) + 8 * (m2 >> 1) + 4 * hi;
      *(uint32_t*)(O + base + d) =
          cvt_pk_bf16(oacc[ds][2 * m2] * inv, oacc[ds][2 * m2 + 1] * inv);
    }
}

// ---------------- launcher ----------------
extern "C" void kernel_launch(void* const* d_in, const int* in_sizes, int n_in,
                              void* d_out, int out_size, void* d_ws, size_t ws_size,
                              hipStream_t stream)
{
  (void)in_sizes; (void)n_in; (void)out_size; (void)ws_size;
  const float* x  = (const float*)d_in[0];
  const float* Wq = (const float*)d_in[2];
  const float* bq = (const float*)d_in[3];
  const float* Wk = (const float*)d_in[4];
  const float* Wv = (const float*)d_in[5];
  const float* bv = (const float*)d_in[6];
  const float* Wo = (const float*)d_in[7];
  const float* bo = (const float*)d_in[8];

  char* ws = (char*)d_ws;
  unsigned short* xb  = (unsigned short*)(ws);               // 16MB (reused for attn out)
  unsigned short* wqb = (unsigned short*)(ws + (16u << 20)); // Wq,Wk,Wv,Wo contiguous
  unsigned short* wkb = wqb + (1u << 20);
  unsigned short* wvb = wkb + (1u << 20);
  unsigned short* wob = wvb + (1u << 20);
  unsigned short* qb_ = (unsigned short*)(ws + (24u << 20)); // Q,K,V contiguous 16MB each
  unsigned short* kb_ = (unsigned short*)(ws + (40u << 20));
  unsigned short* vb_ = (unsigned short*)(ws + (56u << 20));

  cvt_kernel<<<2048, 256, 0, stream>>>(x,  xb,  MROWS * NSTATE / 4);
  cvt4_kernel<<<2048, 256, 0, stream>>>(Wq, Wk, Wv, Wo, wqb, wkb, wvb, wob);

  gemm_qkv<<<dim3(24, MROWS / 128), 256, 0, stream>>>(xb, wqb, bq, bv, qb_);

  flash_attn<<<dim3(BATCH * NHEAD, 16), 256, 0, stream>>>(qb_, kb_, vb_, xb);

  gemm_out<<<dim3(NSTATE / 128, MROWS / 128), 256, 0, stream>>>(xb, wob, bo, (float*)d_out);
}